// Round 2
// baseline (55.622 us; speedup 1.0000x reference)
//
#include <hip/hip_runtime.h>

#ifndef FLT_MAX
#define FLT_MAX 3.402823466e+38f
#endif

// Broadcast lane j's float VGPR to all lanes via v_readlane (VALU pipe, no LDS).
__device__ __forceinline__ float rlane(float v, int j) {
    return __uint_as_float(__builtin_amdgcn_readlane(__float_as_uint(v), j));
}

__device__ __forceinline__ float sel3(int i, float a, float b, float c) {
    return i == 0 ? a : (i == 1 ? b : c);
}

// One 64-lane wave per edge; 4 edges per 256-thread block. No LDS at all:
// the 64x64 pair scan broadcasts x2[j] from lane j's registers with
// v_readlane_b32 (immediate lane index in the fully-unrolled loop).
__global__ __launch_bounds__(256) void clustgeo_edge_kernel(
    const float* __restrict__ data,    // (N,4) f32; coords = cols 1..3
    const int*   __restrict__ clusts,  // (C,64) int (harness-converted from i64)
    const int*   __restrict__ eidx,    // (2,E)  int
    float*       __restrict__ out,     // (E,19) f32
    int E)
{
    const int wave = threadIdx.x >> 6;
    const int lane = threadIdx.x & 63;
    const int e = blockIdx.x * 4 + wave;
    if (e >= E) return;

    const int a = eidx[e];
    const int b = eidx[E + e];
    const int p1 = clusts[a * 64 + lane];
    const int p2 = clusts[b * 64 + lane];
    const float4 r1 = *reinterpret_cast<const float4*>(data + (size_t)p1 * 4);
    const float4 r2 = *reinterpret_cast<const float4*>(data + (size_t)p2 * 4);
    const float x1x = r1.y, x1y = r1.z, x1z = r1.w;
    const float x2x = r2.y, x2y = r2.z, x2z = r2.w;

    // Per-lane scan over j: strict < keeps the FIRST minimum (numpy argmin).
    // __f*_rn pins exact f32 mul/add order (no FMA) so near-ties resolve
    // identically to the numpy reference. (sx - x1x) is negated dx; the
    // square is identical bit-for-bit.
    float best = FLT_MAX;
    int bj = 0;
    #pragma unroll
    for (int j = 0; j < 64; ++j) {
        const float sx = rlane(x2x, j);
        const float sy = rlane(x2y, j);
        const float sz = rlane(x2z, j);
        const float dx = __fsub_rn(x1x, sx);
        const float dy = __fsub_rn(x1y, sy);
        const float dz = __fsub_rn(x1z, sz);
        const float d2 = __fadd_rn(__fadd_rn(__fmul_rn(dx, dx), __fmul_rn(dy, dy)),
                                   __fmul_rn(dz, dz));
        if (d2 < best) { best = d2; bj = j; }
    }
    int idx = (lane << 6) | bj;  // flattened i*64+j (i-major, matches reshape)

    // 64-lane butterfly reduce: min value, ties -> lowest flattened index.
    #pragma unroll
    for (int off = 32; off > 0; off >>= 1) {
        const float ov = __shfl_xor(best, off, 64);
        const int   oi = __shfl_xor(idx,  off, 64);
        if (ov < best || (ov == best && oi < idx)) { best = ov; idx = oi; }
    }

    const int i1 = idx >> 6;   // uniform across the wave after the butterfly
    const int i2 = idx & 63;
    const float v1x = rlane(x1x, i1);
    const float v1y = rlane(x1y, i1);
    const float v1z = rlane(x1z, i1);
    const float v2x = rlane(x2x, i2);
    const float v2y = rlane(x2y, i2);
    const float v2z = rlane(x2z, i2);

    float dx = v1x - v2x, dy = v1y - v2y, dz = v1z - v2z;
    const float lend = sqrtf(dx * dx + dy * dy + dz * dz);
    if (lend > 0.f) { dx /= lend; dy /= lend; dz /= lend; }

    if (lane < 19) {
        float o;
        if (lane < 3)       o = sel3(lane,     v1x, v1y, v1z);
        else if (lane < 6)  o = sel3(lane - 3, v2x, v2y, v2z);
        else if (lane < 9)  o = sel3(lane - 6, dx, dy, dz);
        else if (lane == 9) o = lend;
        else {
            const int k = lane - 10;
            o = sel3(k / 3, dx, dy, dz) * sel3(k % 3, dx, dy, dz);
        }
        out[(size_t)e * 19 + lane] = o;
    }
}

extern "C" void kernel_launch(void* const* d_in, const int* in_sizes, int n_in,
                              void* d_out, int out_size, void* d_ws, size_t ws_size,
                              hipStream_t stream) {
    const float* data   = (const float*)d_in[0];
    const int*   clusts = (const int*)d_in[1];
    const int*   eidx   = (const int*)d_in[2];
    float*       out    = (float*)d_out;
    const int E = in_sizes[2] / 2;           // edge_index is (2, E)
    const int blocks = (E + 3) / 4;          // 4 edges (waves) per block
    clustgeo_edge_kernel<<<blocks, 256, 0, stream>>>(data, clusts, eidx, out, E);
}